// Round 12
// baseline (317.275 us; speedup 1.0000x reference)
//
#include <hip/hip_runtime.h>
#include <math.h>

// Problem constants
#define B_    32
#define C3_   1024
#define C4_   2048
#define C_    3072
#define P_    784      // 28*28
#define Q_    196      // 14*14
#define L_    9
#define NG_   25088    // B_*P_
#define A_    312
#define NC_   200

// d_out layout (floats): attr(32x312), class(32x200), maps(32x9x784), af(32x3072x9)
#define ATTR_OFF  0
#define CLASS_OFF 9984
#define MAPS_OFF  16384
#define AF_OFF    242176

// workspace layout (floats)
#define ASQ_OFF   0
#define MF_OFF    16
#define LOGITS_OFF 98320                          // 9 x NG_ = 225792
#define Y_OFF     (LOGITS_OFF + 9 * NG_)          // 324112 ; 32 x 9 x 196
// NOTE: zK zeroes [LOGITS_OFF, Y_OFF+32*9*Q_) as ONE contiguous float4 range
// (282240 floats = 70560 float4) -- logits and Y must stay adjacent.

typedef __attribute__((ext_vector_type(8))) short bf16x8;
typedef __attribute__((ext_vector_type(4))) float f32x4;

__device__ __forceinline__ short f2bf(float f) {
    union { float f; unsigned u; } v; v.f = f;
    unsigned r = v.u + 0x7FFFu + ((v.u >> 16) & 1u);   // RNE
    return (short)(r >> 16);
}

// async global->LDS, 16B per lane, LDS dest = uniform base + lane*16
#define GLDS16(gp, lp) __builtin_amdgcn_global_load_lds(                    \
        (const __attribute__((address_space(1))) unsigned int*)(gp),        \
        (__attribute__((address_space(3))) unsigned int*)(lp), 16, 0, 0)

// ============ zK (v9): blocks 0..8 compute asq[l] in parallel (float4);
// blocks 9..284 zero logits+Y as float4 (70560 vecs).
__global__ __launch_bounds__(256) void zK(const float* __restrict__ conv_w,
                                          float* __restrict__ zbase,
                                          float* __restrict__ asq) {
    int bx = blockIdx.x, t = threadIdx.x;
    if (bx < 9) {
        __shared__ float red[256];
        const float4* w = (const float4*)(conv_w + (size_t)bx * C_);
        float s = 0.f;
#pragma unroll
        for (int i = 0; i < 3; ++i) {        // 768 float4 = 3 x 256
            float4 v = w[t + i * 256];
            s += v.x + v.y + v.z + v.w;
        }
        red[t] = s; __syncthreads();
        for (int o = 128; o > 0; o >>= 1) {
            if (t < o) red[t] += red[t + o];
            __syncthreads();
        }
        if (t == 0) asq[bx] = red[0];
        return;
    }
    int i = (bx - 9) * 256 + t;
    if (i < 70560)
        ((float4*)zbase)[i] = make_float4(0.f, 0.f, 0.f, 0.f);
}

// ============================================================= K_A (round-4)
// Best measured engine (65us): chunked GLDS pipeline, 2x16KB LDS dbuf
// (5 blk/CU), 64ch = 4 chunks of 16, counted vmcnt(4), device-scope atomic
// epilogue into logits (x2) / Y.
//   blocks [0,1568): l3.  slab = bid/98, g-tile = bid%98.
//   blocks [1568,2592): l4. b = idx>>5, grp = idx&31.
__global__ __launch_bounds__(256, 5) void kA(
        const float* __restrict__ l3, const float* __restrict__ l4,
        const float* __restrict__ conv_w,
        float* __restrict__ logits, float* __restrict__ Y) {
    __shared__ float X[2][16 * 256];   // 32768 B -> 5 blocks/CU
    int bid = blockIdx.x;
    int t = threadIdx.x;
    int wave = t >> 6, lane = t & 63;

    bool isl3 = (bid < 1568);
    int slab = 0, g0 = 0, b = 0, grp = 0, cbase_w;
    const float* gbase;     // per-lane base address for channel-row 0
    size_t rowpitch;
    if (isl3) {
        slab = bid / 98;                 // block-uniform
        g0 = (bid % 98) * 256;
        int gidx = g0 + lane * 4;        // 4 floats (16B) per lane
        int bb = gidx / 784, px = gidx % 784;   // 4 | 784 -> no group split
        gbase = l3 + ((size_t)bb * C3_ + slab * 64) * P_ + px;
        rowpitch = P_;
        cbase_w = C4_ + slab * 64;
    } else {
        int idx = bid - 1568;
        b = idx >> 5; grp = idx & 31;    // block-uniform
        int q = lane * 4;
        if (q > 192) q = 192;            // lanes 49..63: dup same 16B (1 line)
        gbase = l4 + ((size_t)b * C4_ + grp * 64) * Q_ + q;
        rowpitch = Q_;
        cbase_w = grp * 64;
    }

    // prologue: chunk 0 -> buf 0 (wave w stages in-chunk rows w*4..w*4+3)
#pragma unroll
    for (int r = 0; r < 4; ++r) {
        int row = wave * 4 + r;
        GLDS16(gbase + (size_t)row * rowpitch, &X[0][row * 256]);
    }

    float acc[9];
#pragma unroll
    for (int l = 0; l < 9; ++l) acc[l] = 0.f;

#pragma unroll
    for (int j = 0; j < 4; ++j) {
        const int cur = j & 1;
        if (j < 3) {
#pragma unroll
            for (int r = 0; r < 4; ++r) {
                int row = wave * 4 + r;           // in-chunk row
                int ch = (j + 1) * 16 + row;      // global channel row
                GLDS16(gbase + (size_t)ch * rowpitch, &X[cur ^ 1][row * 256]);
            }
            // counted wait: own chunk-j loads (oldest 4) done; chunk j+1's
            // 4 loads stay in flight across the barrier.
            asm volatile("s_waitcnt vmcnt(4)" ::: "memory");
        } else {
            asm volatile("s_waitcnt vmcnt(0)" ::: "memory");
        }
        __builtin_amdgcn_s_barrier();      // all waves' chunk-j rows in LDS

        if (isl3 || t < 196) {
#pragma unroll
            for (int c = 0; c < 16; ++c) {
                float x = X[cur][c * 256 + t];
#pragma unroll
                for (int l = 0; l < 9; ++l)
                    acc[l] = fmaf(conv_w[(size_t)l * C_ + cbase_w + j * 16 + c],
                                  x, acc[l]);
            }
        }
        __builtin_amdgcn_s_barrier();      // reads done before buf reuse
    }

    if (isl3) {
#pragma unroll
        for (int l = 0; l < 9; ++l)
            atomicAdd(&logits[(size_t)l * NG_ + g0 + t], 2.f * acc[l]);
    } else if (t < 196) {
#pragma unroll
        for (int l = 0; l < 9; ++l)
            atomicAdd(&Y[((size_t)b * 9 + l) * Q_ + t], acc[l]);
    }
}

// ====== K_C (round-9, reverted): maps = softmax_l( logits + 2*up(Y) - asq )
// Round-10 lesson: the 32-block kCD fusion destroyed parallelism (+25us).
// 98 blocks, one thread per (b,p).
__global__ __launch_bounds__(256) void kC(const float* __restrict__ logits,
                                          const float* __restrict__ Y,
                                          const float* __restrict__ asq,
                                          float* __restrict__ out_maps) {
    int g = blockIdx.x * 256 + threadIdx.x;   // 98 blocks, exact fit
    int b = g / P_, p = g % P_;
    int yy = p / 28, xx = p % 28;
    float sy = 0.5f * yy - 0.25f, sx = 0.5f * xx - 0.25f;
    float fyf = floorf(sy), fxf = floorf(sx);
    float fy = sy - fyf, fx = sx - fxf;
    int ya = max(0, (int)fyf), yb = min(13, (int)fyf + 1);
    int xa = max(0, (int)fxf), xb = min(13, (int)fxf + 1);
    float w00 = (1.f - fy) * (1.f - fx), w01 = (1.f - fy) * fx;
    float w10 = fy * (1.f - fx),         w11 = fy * fx;
    float v[9];
#pragma unroll
    for (int l = 0; l < 9; ++l) {
        const float* Yl = Y + ((size_t)b * 9 + l) * Q_;
        float ab4 = w00 * Yl[ya * 14 + xa] + w01 * Yl[ya * 14 + xb]
                  + w10 * Yl[yb * 14 + xa] + w11 * Yl[yb * 14 + xb];
        v[l] = logits[(size_t)l * NG_ + g] + 2.f * ab4 - asq[l];
    }
    float m = v[0];
#pragma unroll
    for (int l = 1; l < 9; ++l) m = fmaxf(m, v[l]);
    float sum = 0.f;
#pragma unroll
    for (int l = 0; l < 9; ++l) { v[l] = expf(v[l] - m); sum += v[l]; }
    float inv = 1.f / sum;
#pragma unroll
    for (int l = 0; l < 9; ++l)
        out_maps[(size_t)b * (L_ * P_) + l * P_ + p] = v[l] * inv;
}

// ============== adjoint bilinear taps (used inside kE's l4 path now)
__device__ __forceinline__ int adj_taps(int q, int* ys, float* wy) {
    if (q == 0)  { ys[0] = 0;  wy[0] = 1.00f; ys[1] = 1;  wy[1] = 0.75f;
                   ys[2] = 2;  wy[2] = 0.25f; return 3; }
    if (q == 13) { ys[0] = 25; wy[0] = 0.25f; ys[1] = 26; wy[1] = 0.75f;
                   ys[2] = 27; wy[2] = 1.00f; return 3; }
    ys[0] = 2 * q - 1; wy[0] = 0.25f;
    ys[1] = 2 * q;     wy[1] = 0.75f;
    ys[2] = 2 * q + 1; wy[2] = 0.75f;
    ys[3] = 2 * q + 2; wy[3] = 0.25f;
    return 4;
}

// ===================== K_E (v11): direct-global MFMA; kD folded into l4 path
// l4-blocks compute their own Mp[b] (adjoint downsample of L2-hot maps) into
// LDS (7KB, 1764 outputs x ~14 FMA = trivial; 32x redundant per b but maps
// is L2-resident) -> kD kernel + launch deleted, no parallelism lost.
// blocks [0,512): l3 (heavy, 4 K-chunks) FIRST; b=bid>>4, grp 0..15.
// blocks [512,1536): l4, b=idx>>5, grp 0..31, K=196 vs LDS-Mp.
// Epilogue: af FINAL (/784) + mf via 16-lane shfl tree.
__global__ __launch_bounds__(256, 3) void kE(
        const float* __restrict__ l3, const float* __restrict__ l4,
        const float* __restrict__ maps, const float* __restrict__ mod,
        float* __restrict__ out_af, float* __restrict__ mf) {
    __shared__ float sMp[9 * Q_];     // 7056 B (l4 path only)
    int bid = blockIdx.x;
    int t = threadIdx.x;
    int wave = t >> 6, lane = t & 63;
    int row16 = lane & 15, quad = lane >> 4;

    bool isl3 = (bid < 512);
    int b, c0, nchunk, cglob0, pitch;
    const float* xsrc;
    const float* brow;                // B-operand row (global maps or LDS Mp)
    if (isl3) {
        b = bid >> 4; c0 = (bid & 15) * 64; nchunk = 4;
        xsrc = l3 + ((size_t)b * C3_ + c0) * P_;
        pitch = P_;
        cglob0 = C4_ + c0;
        brow = maps + (size_t)b * (L_ * P_) + (size_t)row16 * P_;
    } else {
        int idx = bid - 512;
        b = idx >> 5; c0 = (idx & 31) * 64; nchunk = 1;
        xsrc = l4 + ((size_t)b * C4_ + c0) * Q_;
        pitch = Q_;
        cglob0 = c0;
        // ---- compute Mp[b] into LDS (was kernel kD) ----
        const float* mbase = maps + (size_t)b * (L_ * P_);
        for (int r = t; r < 9 * Q_; r += 256) {
            int l = r / Q_, q = r % Q_;
            int qy = q / 14, qx = q % 14;
            int ys[4], xs[4]; float wy[4], wx[4];
            int ny = adj_taps(qy, ys, wy);
            int nx = adj_taps(qx, xs, wx);
            const float* mrow = mbase + l * P_;
            float s = 0.f;
            for (int i = 0; i < ny; ++i) {
                float rs = 0.f;
                for (int j = 0; j < nx; ++j)
                    rs = fmaf(wx[j], mrow[ys[i] * 28 + xs[j]], rs);
                s = fmaf(wy[i], rs, s);
            }
            sMp[r] = s;
        }
        __syncthreads();              // block-uniform path: legal
        brow = sMp + row16 * Q_;
    }
    const float* arow = xsrc + (size_t)(wave * 16 + row16) * pitch;

    f32x4 acc = {0.f, 0.f, 0.f, 0.f};
    for (int h = 0; h < nchunk; ++h) {
        int koff = h * 196;
        float4 a[13];
#pragma unroll
        for (int s = 0; s < 6; ++s) {
            int k0 = koff + s * 32 + quad * 8;
            a[2 * s]     = *(const float4*)(arow + k0);
            a[2 * s + 1] = *(const float4*)(arow + k0 + 4);
        }
        a[12] = make_float4(0.f, 0.f, 0.f, 0.f);
        if (quad == 0) a[12] = *(const float4*)(arow + koff + 192);

        bf16x8 bfr[7];
#pragma unroll
        for (int s = 0; s < 7; ++s) {
            int k0 = s * 32 + quad * 8;
            bf16x8 bv = {0, 0, 0, 0, 0, 0, 0, 0};
            if (row16 < 9) {
                const float* bp = brow + koff + k0;
                if (s < 6) {
                    float4 b0 = *(const float4*)(bp);
                    float4 b1 = *(const float4*)(bp + 4);
                    bv[0] = f2bf(b0.x); bv[1] = f2bf(b0.y);
                    bv[2] = f2bf(b0.z); bv[3] = f2bf(b0.w);
                    bv[4] = f2bf(b1.x); bv[5] = f2bf(b1.y);
                    bv[6] = f2bf(b1.z); bv[7] = f2bf(b1.w);
                } else if (quad == 0) {        // k0=192: cols 192..195 only
                    float4 b0 = *(const float4*)(bp);
                    bv[0] = f2bf(b0.x); bv[1] = f2bf(b0.y);
                    bv[2] = f2bf(b0.z); bv[3] = f2bf(b0.w);
                }
            }
            bfr[s] = bv;
        }

#pragma unroll
        for (int s = 0; s < 7; ++s) {
            bf16x8 av = {0, 0, 0, 0, 0, 0, 0, 0};
            if (s < 6) {
                float4 a0 = a[2 * s], a1 = a[2 * s + 1];
                av[0] = f2bf(a0.x); av[1] = f2bf(a0.y);
                av[2] = f2bf(a0.z); av[3] = f2bf(a0.w);
                av[4] = f2bf(a1.x); av[5] = f2bf(a1.y);
                av[6] = f2bf(a1.z); av[7] = f2bf(a1.w);
            } else if (quad == 0) {
                float4 a0 = a[12];
                av[0] = f2bf(a0.x); av[1] = f2bf(a0.y);
                av[2] = f2bf(a0.z); av[3] = f2bf(a0.w);
            }
            acc = __builtin_amdgcn_mfma_f32_16x16x32_bf16(av, bfr[s], acc,
                                                          0, 0, 0);
        }
    }

    // ---- epilogue: af (final) + mf (verified r4/r7 scheme) ----
    int l = row16;
    int cg = cglob0 + wave * 16 + quad * 4;
    float afv[4];
#pragma unroll
    for (int r = 0; r < 4; ++r) afv[r] = acc[r] * (1.f / 784.f);
    if (l < 9) {
        size_t base = ((size_t)b * C_ + cg) * 9 + l;
#pragma unroll
        for (int r = 0; r < 4; ++r) out_af[base + (size_t)r * 9] = afv[r];
    }
    float term[4];
#pragma unroll
    for (int r = 0; r < 4; ++r)
        term[r] = (l < 8) ? afv[r] * mod[(size_t)(cg + r) * 9 + l] : 0.f;
#pragma unroll
    for (int s = 1; s < 16; s <<= 1)
#pragma unroll
        for (int r = 0; r < 4; ++r) term[r] += __shfl_xor(term[r], s);
    if (row16 == 0) {
#pragma unroll
        for (int r = 0; r < 4; ++r)
            mf[(size_t)b * C_ + cg + r] = term[r] * 0.125f;
    }
}

// ============== K_F (v9): attr = mf @ attr_w.T, attr_w staged ONCE per block
__global__ __launch_bounds__(256) void kF(
        const float* __restrict__ mf, const float* __restrict__ attr_w,
        const float* __restrict__ attr_b, float* __restrict__ out_attr) {
    __shared__ float sw[C_];               // 12288 B
    int a = blockIdx.x, t = threadIdx.x;
    const float4* wr = (const float4*)(attr_w + (size_t)a * C_);
#pragma unroll
    for (int i = 0; i < 3; ++i)            // 768 float4 = 3 x 256
        ((float4*)sw)[t + i * 256] = wr[t + i * 256];
    __syncthreads();

    int b = t >> 3, j = t & 7;             // 8 lanes per batch
    const float* mrow = mf + (size_t)b * C_;
    float acc = 0.f;
#pragma unroll 8
    for (int m = 0; m < 96; ++m) {         // k = j*4 + m*32 covers K once
        int k = j * 4 + m * 32;
        float4 mv = *(const float4*)(mrow + k);
        float4 wv = *(const float4*)(sw + k);   // broadcast across b-groups
        acc += mv.x * wv.x + mv.y * wv.y + mv.z * wv.z + mv.w * wv.w;
    }
    acc += __shfl_xor(acc, 1);
    acc += __shfl_xor(acc, 2);
    acc += __shfl_xor(acc, 4);
    if (j == 0) out_attr[(size_t)b * A_ + a] = acc + attr_b[a];
}

// ---------------------------------------------- K_G: class = attr @ class_w.T
__global__ __launch_bounds__(256) void kG(
        const float* __restrict__ attr, const float* __restrict__ class_w,
        float* __restrict__ out_class) {
    int idx = blockIdx.x * 4 + (threadIdx.x >> 6);   // idx = b*200 + n
    int lane = threadIdx.x & 63;
    int b = idx / NC_, n = idx % NC_;
    float acc = 0.f;
    for (int a = lane; a < A_; a += 64)
        acc += attr[b * A_ + a] * class_w[n * A_ + a];
    acc += __shfl_xor(acc, 1);  acc += __shfl_xor(acc, 2);
    acc += __shfl_xor(acc, 4);  acc += __shfl_xor(acc, 8);
    acc += __shfl_xor(acc, 16); acc += __shfl_xor(acc, 32);
    if (lane == 0) out_class[idx] = acc;
}

extern "C" void kernel_launch(void* const* d_in, const int* in_sizes, int n_in,
                              void* d_out, int out_size, void* d_ws, size_t ws_size,
                              hipStream_t stream) {
    (void)in_sizes; (void)n_in; (void)out_size; (void)ws_size;
    const float* l3         = (const float*)d_in[0];
    const float* l4         = (const float*)d_in[1];
    const float* conv_w     = (const float*)d_in[2];
    const float* modulation = (const float*)d_in[3];
    const float* attr_w     = (const float*)d_in[4];
    const float* attr_b     = (const float*)d_in[5];
    const float* class_w    = (const float*)d_in[6];
    float* out = (float*)d_out;
    float* ws  = (float*)d_ws;
    float* asq    = ws + ASQ_OFF;
    float* mf     = ws + MF_OFF;
    float* logits = ws + LOGITS_OFF;
    float* Y      = ws + Y_OFF;

    zK<<<285, 256, 0, stream>>>(conv_w, logits /* zero base: logits+Y */, asq);
    kA<<<2592, 256, 0, stream>>>(l3, l4, conv_w, logits, Y);
    kC<<<98, 256, 0, stream>>>(logits, Y, asq, out + MAPS_OFF);
    kE<<<1536, 256, 0, stream>>>(l3, l4, out + MAPS_OFF, modulation,
                                 out + AF_OFF, mf);
    kF<<<A_, 256, 0, stream>>>(mf, attr_w, attr_b, out + ATTR_OFF);
    kG<<<(B_ * NC_) / 4, 256, 0, stream>>>(out + ATTR_OFF, class_w,
                                           out + CLASS_OFF);
}

// Round 13
// 268.681 us; speedup vs baseline: 1.1809x; 1.1809x over previous
//
#include <hip/hip_runtime.h>
#include <math.h>

// Problem constants
#define B_    32
#define C3_   1024
#define C4_   2048
#define C_    3072
#define P_    784      // 28*28
#define Q_    196      // 14*14
#define L_    9
#define NG_   25088    // B_*P_
#define A_    312
#define NC_   200

// d_out layout (floats): attr(32x312), class(32x200), maps(32x9x784), af(32x3072x9)
#define ATTR_OFF  0
#define CLASS_OFF 9984
#define MAPS_OFF  16384
#define AF_OFF    242176

// workspace layout (floats)
#define ASQ_OFF   0
#define MF_OFF    16
#define LOGITS_OFF 98320                          // 9 x NG_ = 225792
#define Y_OFF     (LOGITS_OFF + 9 * NG_)          // 324112 ; 32 x 9 x 196
#define MP_OFF    (Y_OFF + 32 * 9 * Q_)           // 380560 ; 32 x 9 x 196
// NOTE: zK zeroes [LOGITS_OFF, Y_OFF+32*9*Q_) as ONE contiguous float4 range
// (282240 floats = 70560 float4) -- logits and Y must stay adjacent.

typedef __attribute__((ext_vector_type(8))) short bf16x8;
typedef __attribute__((ext_vector_type(4))) float f32x4;

__device__ __forceinline__ short f2bf(float f) {
    union { float f; unsigned u; } v; v.f = f;
    unsigned r = v.u + 0x7FFFu + ((v.u >> 16) & 1u);   // RNE
    return (short)(r >> 16);
}

// async global->LDS, 16B per lane, LDS dest = uniform base + lane*16
#define GLDS16(gp, lp) __builtin_amdgcn_global_load_lds(                    \
        (const __attribute__((address_space(1))) unsigned int*)(gp),        \
        (__attribute__((address_space(3))) unsigned int*)(lp), 16, 0, 0)

// ============ zK (v9): blocks 0..8 compute asq[l] in parallel (float4);
// blocks 9..284 zero logits+Y as float4 (70560 vecs).
__global__ __launch_bounds__(256) void zK(const float* __restrict__ conv_w,
                                          float* __restrict__ zbase,
                                          float* __restrict__ asq) {
    int bx = blockIdx.x, t = threadIdx.x;
    if (bx < 9) {
        __shared__ float red[256];
        const float4* w = (const float4*)(conv_w + (size_t)bx * C_);
        float s = 0.f;
#pragma unroll
        for (int i = 0; i < 3; ++i) {        // 768 float4 = 3 x 256
            float4 v = w[t + i * 256];
            s += v.x + v.y + v.z + v.w;
        }
        red[t] = s; __syncthreads();
        for (int o = 128; o > 0; o >>= 1) {
            if (t < o) red[t] += red[t + o];
            __syncthreads();
        }
        if (t == 0) asq[bx] = red[0];
        return;
    }
    int i = (bx - 9) * 256 + t;
    if (i < 70560)
        ((float4*)zbase)[i] = make_float4(0.f, 0.f, 0.f, 0.f);
}

// ============================================================= K_A (round-4)
// Best measured engine (65us): chunked GLDS pipeline, 2x16KB LDS dbuf
// (5 blk/CU), 64ch = 4 chunks of 16, counted vmcnt(4), device-scope atomic
// epilogue into logits (x2) / Y.
//   blocks [0,1568): l3.  slab = bid/98, g-tile = bid%98.
//   blocks [1568,2592): l4. b = idx>>5, grp = idx&31.
__global__ __launch_bounds__(256, 5) void kA(
        const float* __restrict__ l3, const float* __restrict__ l4,
        const float* __restrict__ conv_w,
        float* __restrict__ logits, float* __restrict__ Y) {
    __shared__ float X[2][16 * 256];   // 32768 B -> 5 blocks/CU
    int bid = blockIdx.x;
    int t = threadIdx.x;
    int wave = t >> 6, lane = t & 63;

    bool isl3 = (bid < 1568);
    int slab = 0, g0 = 0, b = 0, grp = 0, cbase_w;
    const float* gbase;     // per-lane base address for channel-row 0
    size_t rowpitch;
    if (isl3) {
        slab = bid / 98;                 // block-uniform
        g0 = (bid % 98) * 256;
        int gidx = g0 + lane * 4;        // 4 floats (16B) per lane
        int bb = gidx / 784, px = gidx % 784;   // 4 | 784 -> no group split
        gbase = l3 + ((size_t)bb * C3_ + slab * 64) * P_ + px;
        rowpitch = P_;
        cbase_w = C4_ + slab * 64;
    } else {
        int idx = bid - 1568;
        b = idx >> 5; grp = idx & 31;    // block-uniform
        int q = lane * 4;
        if (q > 192) q = 192;            // lanes 49..63: dup same 16B (1 line)
        gbase = l4 + ((size_t)b * C4_ + grp * 64) * Q_ + q;
        rowpitch = Q_;
        cbase_w = grp * 64;
    }

    // prologue: chunk 0 -> buf 0 (wave w stages in-chunk rows w*4..w*4+3)
#pragma unroll
    for (int r = 0; r < 4; ++r) {
        int row = wave * 4 + r;
        GLDS16(gbase + (size_t)row * rowpitch, &X[0][row * 256]);
    }

    float acc[9];
#pragma unroll
    for (int l = 0; l < 9; ++l) acc[l] = 0.f;

#pragma unroll
    for (int j = 0; j < 4; ++j) {
        const int cur = j & 1;
        if (j < 3) {
#pragma unroll
            for (int r = 0; r < 4; ++r) {
                int row = wave * 4 + r;           // in-chunk row
                int ch = (j + 1) * 16 + row;      // global channel row
                GLDS16(gbase + (size_t)ch * rowpitch, &X[cur ^ 1][row * 256]);
            }
            // counted wait: own chunk-j loads (oldest 4) done; chunk j+1's
            // 4 loads stay in flight across the barrier.
            asm volatile("s_waitcnt vmcnt(4)" ::: "memory");
        } else {
            asm volatile("s_waitcnt vmcnt(0)" ::: "memory");
        }
        __builtin_amdgcn_s_barrier();      // all waves' chunk-j rows in LDS

        if (isl3 || t < 196) {
#pragma unroll
            for (int c = 0; c < 16; ++c) {
                float x = X[cur][c * 256 + t];
#pragma unroll
                for (int l = 0; l < 9; ++l)
                    acc[l] = fmaf(conv_w[(size_t)l * C_ + cbase_w + j * 16 + c],
                                  x, acc[l]);
            }
        }
        __builtin_amdgcn_s_barrier();      // reads done before buf reuse
    }

    if (isl3) {
#pragma unroll
        for (int l = 0; l < 9; ++l)
            atomicAdd(&logits[(size_t)l * NG_ + g0 + t], 2.f * acc[l]);
    } else if (t < 196) {
#pragma unroll
        for (int l = 0; l < 9; ++l)
            atomicAdd(&Y[((size_t)b * 9 + l) * Q_ + t], acc[l]);
    }
}

// ====== K_C (round-9): maps = softmax_l( logits + 2*up(Y) - asq ), 98 blocks
__global__ __launch_bounds__(256) void kC(const float* __restrict__ logits,
                                          const float* __restrict__ Y,
                                          const float* __restrict__ asq,
                                          float* __restrict__ out_maps) {
    int g = blockIdx.x * 256 + threadIdx.x;   // 98 blocks, exact fit
    int b = g / P_, p = g % P_;
    int yy = p / 28, xx = p % 28;
    float sy = 0.5f * yy - 0.25f, sx = 0.5f * xx - 0.25f;
    float fyf = floorf(sy), fxf = floorf(sx);
    float fy = sy - fyf, fx = sx - fxf;
    int ya = max(0, (int)fyf), yb = min(13, (int)fyf + 1);
    int xa = max(0, (int)fxf), xb = min(13, (int)fxf + 1);
    float w00 = (1.f - fy) * (1.f - fx), w01 = (1.f - fy) * fx;
    float w10 = fy * (1.f - fx),         w11 = fy * fx;
    float v[9];
#pragma unroll
    for (int l = 0; l < 9; ++l) {
        const float* Yl = Y + ((size_t)b * 9 + l) * Q_;
        float ab4 = w00 * Yl[ya * 14 + xa] + w01 * Yl[ya * 14 + xb]
                  + w10 * Yl[yb * 14 + xa] + w11 * Yl[yb * 14 + xb];
        v[l] = logits[(size_t)l * NG_ + g] + 2.f * ab4 - asq[l];
    }
    float m = v[0];
#pragma unroll
    for (int l = 1; l < 9; ++l) m = fmaxf(m, v[l]);
    float sum = 0.f;
#pragma unroll
    for (int l = 0; l < 9; ++l) { v[l] = expf(v[l] - m); sum += v[l]; }
    float inv = 1.f / sum;
#pragma unroll
    for (int l = 0; l < 9; ++l)
        out_maps[(size_t)b * (L_ * P_) + l * P_ + p] = v[l] * inv;
}

// ============== K_D (round-9): adjoint bilinear downsample maps -> Mp[b,l,q]
// Round-12 lesson: folding this into kE's 1024 l4-blocks (32x redundant
// recompute + syncthreads) cost ~35us; the dedicated 221-block kernel wins.
__device__ __forceinline__ int adj_taps(int q, int* ys, float* wy) {
    if (q == 0)  { ys[0] = 0;  wy[0] = 1.00f; ys[1] = 1;  wy[1] = 0.75f;
                   ys[2] = 2;  wy[2] = 0.25f; return 3; }
    if (q == 13) { ys[0] = 25; wy[0] = 0.25f; ys[1] = 26; wy[1] = 0.75f;
                   ys[2] = 27; wy[2] = 1.00f; return 3; }
    ys[0] = 2 * q - 1; wy[0] = 0.25f;
    ys[1] = 2 * q;     wy[1] = 0.75f;
    ys[2] = 2 * q + 1; wy[2] = 0.75f;
    ys[3] = 2 * q + 2; wy[3] = 0.25f;
    return 4;
}

__global__ __launch_bounds__(256) void kD(const float* __restrict__ maps,
                                          float* __restrict__ Mp) {
    int tid = blockIdx.x * 256 + threadIdx.x;
    if (tid >= 32 * 9 * Q_) return;
    int b = tid / (9 * Q_);
    int r = tid % (9 * Q_);
    int l = r / Q_, q = r % Q_;
    int qy = q / 14, qx = q % 14;
    int ys[4], xs[4]; float wy[4], wx[4];
    int ny = adj_taps(qy, ys, wy);
    int nx = adj_taps(qx, xs, wx);
    const float* mrow = maps + (size_t)b * (L_ * P_) + l * P_;
    float s = 0.f;
    for (int i = 0; i < ny; ++i) {
        float rs = 0.f;
        for (int j = 0; j < nx; ++j)
            rs = fmaf(wx[j], mrow[ys[i] * 28 + xs[j]], rs);
        s = fmaf(wy[i], rs, s);
    }
    Mp[(size_t)b * (9 * Q_) + r] = s;
}

// ===================== K_E (v13): round-9 direct-global MFMA + COALESCED
// af write. Round-12 counters exposed ~19x HBM write amplification from the
// old scattered epilogue (4B stores at stride 36B, 36/64 lanes active:
// WRITE_SIZE 73.7MB for 3.9MB of output). Fix: deposit afv into a 2.3KB LDS
// buffer, syncthreads, then 144 coalesced float4 stores covering the block's
// contiguous 576-float af span.
// blocks [0,1024): l4 (b, 32 grps of 64) K=196 vs Mp (round-9 order).
// blocks [1024,1536): l3, b=idx>>4, grp 0..15, K=784 (4 chunks, acc carried).
__global__ __launch_bounds__(256, 3) void kE(
        const float* __restrict__ l3, const float* __restrict__ l4,
        const float* __restrict__ maps, const float* __restrict__ Mp,
        const float* __restrict__ mod,
        float* __restrict__ out_af, float* __restrict__ mf) {
    __shared__ float sAf[576];        // 2304 B: block's 64ch x 9l af tile
    int bid = blockIdx.x;
    int t = threadIdx.x;
    int wave = t >> 6, lane = t & 63;
    int row16 = lane & 15, quad = lane >> 4;

    bool isl4 = (bid < 1024);
    int b, c0, nchunk, cglob0, pitch;
    const float* xsrc; const float* bsrc;
    if (isl4) {
        b = bid >> 5; c0 = (bid & 31) * 64; nchunk = 1;
        xsrc = l4 + ((size_t)b * C4_ + c0) * Q_;
        bsrc = Mp + (size_t)b * (9 * Q_);
        pitch = Q_;
        cglob0 = c0;
    } else {
        int idx = bid - 1024;
        b = idx >> 4; c0 = (idx & 15) * 64; nchunk = 4;
        xsrc = l3 + ((size_t)b * C3_ + c0) * P_;
        bsrc = maps + (size_t)b * (L_ * P_);
        pitch = P_;
        cglob0 = C4_ + c0;
    }
    const float* arow = xsrc + (size_t)(wave * 16 + row16) * pitch;
    const float* brow = bsrc + (size_t)row16 * pitch;   // valid if row16 < 9

    f32x4 acc = {0.f, 0.f, 0.f, 0.f};
    for (int h = 0; h < nchunk; ++h) {
        int koff = h * 196;
        float4 a[13];
#pragma unroll
        for (int s = 0; s < 6; ++s) {
            int k0 = koff + s * 32 + quad * 8;
            a[2 * s]     = *(const float4*)(arow + k0);
            a[2 * s + 1] = *(const float4*)(arow + k0 + 4);
        }
        a[12] = make_float4(0.f, 0.f, 0.f, 0.f);
        if (quad == 0) a[12] = *(const float4*)(arow + koff + 192);

        bf16x8 bfr[7];
#pragma unroll
        for (int s = 0; s < 7; ++s) {
            int k0 = s * 32 + quad * 8;
            bf16x8 bv = {0, 0, 0, 0, 0, 0, 0, 0};
            if (row16 < 9) {
                const float* bp = brow + koff + k0;
                if (s < 6) {
                    float4 b0 = *(const float4*)(bp);
                    float4 b1 = *(const float4*)(bp + 4);
                    bv[0] = f2bf(b0.x); bv[1] = f2bf(b0.y);
                    bv[2] = f2bf(b0.z); bv[3] = f2bf(b0.w);
                    bv[4] = f2bf(b1.x); bv[5] = f2bf(b1.y);
                    bv[6] = f2bf(b1.z); bv[7] = f2bf(b1.w);
                } else if (quad == 0) {        // k0=192: cols 192..195 only
                    float4 b0 = *(const float4*)(bp);
                    bv[0] = f2bf(b0.x); bv[1] = f2bf(b0.y);
                    bv[2] = f2bf(b0.z); bv[3] = f2bf(b0.w);
                }
            }
            bfr[s] = bv;
        }

#pragma unroll
        for (int s = 0; s < 7; ++s) {
            bf16x8 av = {0, 0, 0, 0, 0, 0, 0, 0};
            if (s < 6) {
                float4 a0 = a[2 * s], a1 = a[2 * s + 1];
                av[0] = f2bf(a0.x); av[1] = f2bf(a0.y);
                av[2] = f2bf(a0.z); av[3] = f2bf(a0.w);
                av[4] = f2bf(a1.x); av[5] = f2bf(a1.y);
                av[6] = f2bf(a1.z); av[7] = f2bf(a1.w);
            } else if (quad == 0) {
                float4 a0 = a[12];
                av[0] = f2bf(a0.x); av[1] = f2bf(a0.y);
                av[2] = f2bf(a0.z); av[3] = f2bf(a0.w);
            }
            acc = __builtin_amdgcn_mfma_f32_16x16x32_bf16(av, bfr[s], acc,
                                                          0, 0, 0);
        }
    }

    // ---- epilogue: af via LDS -> coalesced float4; mf via shfl tree ----
    int l = row16;
    int lc = wave * 16 + quad * 4;        // local channel base (0..60)
    float afv[4];
#pragma unroll
    for (int r = 0; r < 4; ++r) afv[r] = acc[r] * (1.f / 784.f);
    if (l < 9) {
#pragma unroll
        for (int r = 0; r < 4; ++r) sAf[(lc + r) * 9 + l] = afv[r];
    }
    int cg = cglob0 + lc;
    float term[4];
#pragma unroll
    for (int r = 0; r < 4; ++r)
        term[r] = (l < 8) ? afv[r] * mod[(size_t)(cg + r) * 9 + l] : 0.f;
#pragma unroll
    for (int s = 1; s < 16; s <<= 1)
#pragma unroll
        for (int r = 0; r < 4; ++r) term[r] += __shfl_xor(term[r], s);
    if (row16 == 0) {
#pragma unroll
        for (int r = 0; r < 4; ++r)
            mf[(size_t)b * C_ + cg + r] = term[r] * 0.125f;
    }
    __syncthreads();
    // block's af span: 576 contiguous floats at (b*C + cglob0)*9
    size_t obase = ((size_t)b * C_ + cglob0) * 9;   // multiple of 4
    if (t < 144)
        ((float4*)(out_af + obase))[t] = ((const float4*)sAf)[t];
}

// ============== K_F (v9): attr = mf @ attr_w.T, attr_w staged ONCE per block
__global__ __launch_bounds__(256) void kF(
        const float* __restrict__ mf, const float* __restrict__ attr_w,
        const float* __restrict__ attr_b, float* __restrict__ out_attr) {
    __shared__ float sw[C_];               // 12288 B
    int a = blockIdx.x, t = threadIdx.x;
    const float4* wr = (const float4*)(attr_w + (size_t)a * C_);
#pragma unroll
    for (int i = 0; i < 3; ++i)            // 768 float4 = 3 x 256
        ((float4*)sw)[t + i * 256] = wr[t + i * 256];
    __syncthreads();

    int b = t >> 3, j = t & 7;             // 8 lanes per batch
    const float* mrow = mf + (size_t)b * C_;
    float acc = 0.f;
#pragma unroll 8
    for (int m = 0; m < 96; ++m) {         // k = j*4 + m*32 covers K once
        int k = j * 4 + m * 32;
        float4 mv = *(const float4*)(mrow + k);
        float4 wv = *(const float4*)(sw + k);   // broadcast across b-groups
        acc += mv.x * wv.x + mv.y * wv.y + mv.z * wv.z + mv.w * wv.w;
    }
    acc += __shfl_xor(acc, 1);
    acc += __shfl_xor(acc, 2);
    acc += __shfl_xor(acc, 4);
    if (j == 0) out_attr[(size_t)b * A_ + a] = acc + attr_b[a];
}

// ---------------------------------------------- K_G: class = attr @ class_w.T
__global__ __launch_bounds__(256) void kG(
        const float* __restrict__ attr, const float* __restrict__ class_w,
        float* __restrict__ out_class) {
    int idx = blockIdx.x * 4 + (threadIdx.x >> 6);   // idx = b*200 + n
    int lane = threadIdx.x & 63;
    int b = idx / NC_, n = idx % NC_;
    float acc = 0.f;
    for (int a = lane; a < A_; a += 64)
        acc += attr[b * A_ + a] * class_w[n * A_ + a];
    acc += __shfl_xor(acc, 1);  acc += __shfl_xor(acc, 2);
    acc += __shfl_xor(acc, 4);  acc += __shfl_xor(acc, 8);
    acc += __shfl_xor(acc, 16); acc += __shfl_xor(acc, 32);
    if (lane == 0) out_class[idx] = acc;
}

extern "C" void kernel_launch(void* const* d_in, const int* in_sizes, int n_in,
                              void* d_out, int out_size, void* d_ws, size_t ws_size,
                              hipStream_t stream) {
    (void)in_sizes; (void)n_in; (void)out_size; (void)ws_size;
    const float* l3         = (const float*)d_in[0];
    const float* l4         = (const float*)d_in[1];
    const float* conv_w     = (const float*)d_in[2];
    const float* modulation = (const float*)d_in[3];
    const float* attr_w     = (const float*)d_in[4];
    const float* attr_b     = (const float*)d_in[5];
    const float* class_w    = (const float*)d_in[6];
    float* out = (float*)d_out;
    float* ws  = (float*)d_ws;
    float* asq    = ws + ASQ_OFF;
    float* mf     = ws + MF_OFF;
    float* logits = ws + LOGITS_OFF;
    float* Y      = ws + Y_OFF;
    float* Mp     = ws + MP_OFF;

    zK<<<285, 256, 0, stream>>>(conv_w, logits /* zero base: logits+Y */, asq);
    kA<<<2592, 256, 0, stream>>>(l3, l4, conv_w, logits, Y);
    kC<<<98, 256, 0, stream>>>(logits, Y, asq, out + MAPS_OFF);
    kD<<<221, 256, 0, stream>>>(out + MAPS_OFF, Mp);
    kE<<<1536, 256, 0, stream>>>(l3, l4, out + MAPS_OFF, Mp, modulation,
                                 out + AF_OFF, mf);
    kF<<<A_, 256, 0, stream>>>(mf, attr_w, attr_b, out + ATTR_OFF);
    kG<<<(B_ * NC_) / 4, 256, 0, stream>>>(out + ATTR_OFF, class_w,
                                           out + CLASS_OFF);
}

// Round 14
// 268.182 us; speedup vs baseline: 1.1831x; 1.0019x over previous
//
#include <hip/hip_runtime.h>
#include <math.h>

// Problem constants
#define B_    32
#define C3_   1024
#define C4_   2048
#define C_    3072
#define P_    784      // 28*28
#define Q_    196      // 14*14
#define L_    9
#define NG_   25088    // B_*P_
#define A_    312
#define NC_   200

// d_out layout (floats): attr(32x312), class(32x200), maps(32x9x784), af(32x3072x9)
#define ATTR_OFF  0
#define CLASS_OFF 9984
#define MAPS_OFF  16384
#define AF_OFF    242176

// workspace layout (floats)
#define ASQ_OFF   0
#define MF_OFF    16
#define LOGITS_OFF 98320                          // 9 x NG_ = 225792
#define Y_OFF     (LOGITS_OFF + 9 * NG_)          // 324112 ; 32 x 9 x 196
#define MP_OFF    (Y_OFF + 32 * 9 * Q_)           // 380560 ; 32 x 9 x 196
// NOTE: zK zeroes [LOGITS_OFF, Y_OFF+32*9*Q_) as ONE contiguous float4 range
// (282240 floats = 70560 float4) -- logits and Y must stay adjacent.

typedef __attribute__((ext_vector_type(8))) short bf16x8;
typedef __attribute__((ext_vector_type(4))) float f32x4;

__device__ __forceinline__ short f2bf(float f) {
    union { float f; unsigned u; } v; v.f = f;
    unsigned r = v.u + 0x7FFFu + ((v.u >> 16) & 1u);   // RNE
    return (short)(r >> 16);
}

// async global->LDS, 16B per lane, LDS dest = uniform base + lane*16
#define GLDS16(gp, lp) __builtin_amdgcn_global_load_lds(                    \
        (const __attribute__((address_space(1))) unsigned int*)(gp),        \
        (__attribute__((address_space(3))) unsigned int*)(lp), 16, 0, 0)

// ============ zK (v9): blocks 0..8 compute asq[l] in parallel (float4);
// blocks 9..284 zero logits+Y as float4 (70560 vecs).
__global__ __launch_bounds__(256) void zK(const float* __restrict__ conv_w,
                                          float* __restrict__ zbase,
                                          float* __restrict__ asq) {
    int bx = blockIdx.x, t = threadIdx.x;
    if (bx < 9) {
        __shared__ float red[256];
        const float4* w = (const float4*)(conv_w + (size_t)bx * C_);
        float s = 0.f;
#pragma unroll
        for (int i = 0; i < 3; ++i) {        // 768 float4 = 3 x 256
            float4 v = w[t + i * 256];
            s += v.x + v.y + v.z + v.w;
        }
        red[t] = s; __syncthreads();
        for (int o = 128; o > 0; o >>= 1) {
            if (t < o) red[t] += red[t + o];
            __syncthreads();
        }
        if (t == 0) asq[bx] = red[0];
        return;
    }
    int i = (bx - 9) * 256 + t;
    if (i < 70560)
        ((float4*)zbase)[i] = make_float4(0.f, 0.f, 0.f, 0.f);
}

// ============================================================= K_A (v14)
// Rounds 0-13: six load engines all plateau at ~2.4-2.6 TB/s CONSUMED rate
// (HBM 1.6 TB/s + L3). Shared property: row-gather reads (1KB pieces of
// 3136B-pitch rows; each block uses 1/3 of every DRAM row it opens).
// v14 theory: DRAM row-buffer locality. l3 path redesigned so each block
// owns a CONTIGUOUS 200KB region: block = (b, 64-ch slab), 8 chunks x 8
// rows (25,088B each, purely sequential GLDS), dbuf, counted vmcnt.
// Thread t owns pixels {t, t+256, t+512} (+768+t if t<16) for all 64 ch.
//   blocks [0,512): l3 new-style. b = bid>>4, slab = bid&15 (slab-fast ->
//                   consecutive bids read consecutive 200KB regions).
//   blocks [512,1536): l4 OLD path (unchanged; only 25MB of the 154MB).
// Epilogue: device-scope atomics into logits (x2) / Y, counts unchanged.
__global__ __launch_bounds__(256, 3) void kA(
        const float* __restrict__ l3, const float* __restrict__ l4,
        const float* __restrict__ conv_w,
        float* __restrict__ logits, float* __restrict__ Y) {
    __shared__ float X[2][8 * 784];    // 2 x 25088 B = 50176 B -> 3 blk/CU
    int bid = blockIdx.x;
    int t = threadIdx.x;
    int wave = t >> 6, lane = t & 63;

    if (bid < 512) {
        // ---------------- l3: contiguous-region engine ----------------
        int b = bid >> 4, slab = bid & 15;            // block-uniform
        const float* region = l3 + ((size_t)b * C3_ + slab * 64) * P_;
        int cbase_w = C4_ + slab * 64;

        // stage chunk cc (8 rows = 6272 floats = 24.5 x 1KB) into buf
        auto stage = [&](int cc, int buf) {
            const float* src = region + (size_t)cc * 6272;
#pragma unroll
            for (int i = 0; i < 6; ++i) {             // j = 0..23 full KB
                int j = i * 4 + wave;
                GLDS16(src + j * 256 + lane * 4, &X[buf][j * 256]);
            }
            if (wave == 3 && lane < 32)               // tail 512B (j=24)
                GLDS16(src + 6144 + lane * 4, &X[buf][6144]);
        };

        stage(0, 0);

        float acc[9][4];
#pragma unroll
        for (int l = 0; l < 9; ++l)
#pragma unroll
            for (int pi = 0; pi < 4; ++pi) acc[l][pi] = 0.f;

        for (int c = 0; c < 8; ++c) {
            int cur = c & 1;
            if (c < 7) {
                stage(c + 1, cur ^ 1);
                // counted wait: chunk-c loads (oldest) done; chunk c+1's
                // stay in flight across the barrier. wave3 issues 7/chunk.
                if (wave == 3)
                    asm volatile("s_waitcnt vmcnt(7)" ::: "memory");
                else
                    asm volatile("s_waitcnt vmcnt(6)" ::: "memory");
            } else {
                asm volatile("s_waitcnt vmcnt(0)" ::: "memory");
            }
            __builtin_amdgcn_s_barrier();

#pragma unroll
            for (int r = 0; r < 8; ++r) {
                float x0 = X[cur][r * 784 + t];
                float x1 = X[cur][r * 784 + t + 256];
                float x2 = X[cur][r * 784 + t + 512];
                float x3 = (t < 16) ? X[cur][r * 784 + 768 + t] : 0.f;
#pragma unroll
                for (int l = 0; l < 9; ++l) {
                    float wv = conv_w[(size_t)l * C_ + cbase_w + c * 8 + r];
                    acc[l][0] = fmaf(wv, x0, acc[l][0]);
                    acc[l][1] = fmaf(wv, x1, acc[l][1]);
                    acc[l][2] = fmaf(wv, x2, acc[l][2]);
                    acc[l][3] = fmaf(wv, x3, acc[l][3]);
                }
            }
            __builtin_amdgcn_s_barrier();      // reads done before buf reuse
        }

        size_t gb = (size_t)b * P_;
#pragma unroll
        for (int l = 0; l < 9; ++l) {
            atomicAdd(&logits[(size_t)l * NG_ + gb + t],       2.f * acc[l][0]);
            atomicAdd(&logits[(size_t)l * NG_ + gb + t + 256], 2.f * acc[l][1]);
            atomicAdd(&logits[(size_t)l * NG_ + gb + t + 512], 2.f * acc[l][2]);
        }
        if (t < 16) {
#pragma unroll
            for (int l = 0; l < 9; ++l)
                atomicAdd(&logits[(size_t)l * NG_ + gb + 768 + t],
                          2.f * acc[l][3]);
        }
        return;
    }

    // ---------------- l4: round-4 engine (unchanged) ----------------
    int idx = bid - 512;
    int b = idx >> 5, grp = idx & 31;    // block-uniform
    int q = lane * 4;
    if (q > 192) q = 192;                // lanes 49..63: dup same 16B (1 line)
    const float* gbase = l4 + ((size_t)b * C4_ + grp * 64) * Q_ + q;
    int cbase_w = grp * 64;

    // prologue: chunk 0 -> buf 0 (wave w stages in-chunk rows w*4..w*4+3)
#pragma unroll
    for (int r = 0; r < 4; ++r) {
        int row = wave * 4 + r;
        GLDS16(gbase + (size_t)row * Q_, &X[0][row * 256]);
    }

    float acc[9];
#pragma unroll
    for (int l = 0; l < 9; ++l) acc[l] = 0.f;

#pragma unroll
    for (int j = 0; j < 4; ++j) {
        const int cur = j & 1;
        if (j < 3) {
#pragma unroll
            for (int r = 0; r < 4; ++r) {
                int row = wave * 4 + r;           // in-chunk row
                int ch = (j + 1) * 16 + row;      // global channel row
                GLDS16(gbase + (size_t)ch * Q_, &X[cur ^ 1][row * 256]);
            }
            asm volatile("s_waitcnt vmcnt(4)" ::: "memory");
        } else {
            asm volatile("s_waitcnt vmcnt(0)" ::: "memory");
        }
        __builtin_amdgcn_s_barrier();

        if (t < 196) {
#pragma unroll
            for (int c = 0; c < 16; ++c) {
                float x = X[cur][c * 256 + t];
#pragma unroll
                for (int l = 0; l < 9; ++l)
                    acc[l] = fmaf(conv_w[(size_t)l * C_ + cbase_w + j * 16 + c],
                                  x, acc[l]);
            }
        }
        __builtin_amdgcn_s_barrier();
    }

    if (t < 196) {
#pragma unroll
        for (int l = 0; l < 9; ++l)
            atomicAdd(&Y[((size_t)b * 9 + l) * Q_ + t], acc[l]);
    }
}

// ====== K_C (round-9): maps = softmax_l( logits + 2*up(Y) - asq ), 98 blocks
__global__ __launch_bounds__(256) void kC(const float* __restrict__ logits,
                                          const float* __restrict__ Y,
                                          const float* __restrict__ asq,
                                          float* __restrict__ out_maps) {
    int g = blockIdx.x * 256 + threadIdx.x;   // 98 blocks, exact fit
    int b = g / P_, p = g % P_;
    int yy = p / 28, xx = p % 28;
    float sy = 0.5f * yy - 0.25f, sx = 0.5f * xx - 0.25f;
    float fyf = floorf(sy), fxf = floorf(sx);
    float fy = sy - fyf, fx = sx - fxf;
    int ya = max(0, (int)fyf), yb = min(13, (int)fyf + 1);
    int xa = max(0, (int)fxf), xb = min(13, (int)fxf + 1);
    float w00 = (1.f - fy) * (1.f - fx), w01 = (1.f - fy) * fx;
    float w10 = fy * (1.f - fx),         w11 = fy * fx;
    float v[9];
#pragma unroll
    for (int l = 0; l < 9; ++l) {
        const float* Yl = Y + ((size_t)b * 9 + l) * Q_;
        float ab4 = w00 * Yl[ya * 14 + xa] + w01 * Yl[ya * 14 + xb]
                  + w10 * Yl[yb * 14 + xa] + w11 * Yl[yb * 14 + xb];
        v[l] = logits[(size_t)l * NG_ + g] + 2.f * ab4 - asq[l];
    }
    float m = v[0];
#pragma unroll
    for (int l = 1; l < 9; ++l) m = fmaxf(m, v[l]);
    float sum = 0.f;
#pragma unroll
    for (int l = 0; l < 9; ++l) { v[l] = expf(v[l] - m); sum += v[l]; }
    float inv = 1.f / sum;
#pragma unroll
    for (int l = 0; l < 9; ++l)
        out_maps[(size_t)b * (L_ * P_) + l * P_ + p] = v[l] * inv;
}

// ============== K_D (round-9): adjoint bilinear downsample maps -> Mp[b,l,q]
__device__ __forceinline__ int adj_taps(int q, int* ys, float* wy) {
    if (q == 0)  { ys[0] = 0;  wy[0] = 1.00f; ys[1] = 1;  wy[1] = 0.75f;
                   ys[2] = 2;  wy[2] = 0.25f; return 3; }
    if (q == 13) { ys[0] = 25; wy[0] = 0.25f; ys[1] = 26; wy[1] = 0.75f;
                   ys[2] = 27; wy[2] = 1.00f; return 3; }
    ys[0] = 2 * q - 1; wy[0] = 0.25f;
    ys[1] = 2 * q;     wy[1] = 0.75f;
    ys[2] = 2 * q + 1; wy[2] = 0.75f;
    ys[3] = 2 * q + 2; wy[3] = 0.25f;
    return 4;
}

__global__ __launch_bounds__(256) void kD(const float* __restrict__ maps,
                                          float* __restrict__ Mp) {
    int tid = blockIdx.x * 256 + threadIdx.x;
    if (tid >= 32 * 9 * Q_) return;
    int b = tid / (9 * Q_);
    int r = tid % (9 * Q_);
    int l = r / Q_, q = r % Q_;
    int qy = q / 14, qx = q % 14;
    int ys[4], xs[4]; float wy[4], wx[4];
    int ny = adj_taps(qy, ys, wy);
    int nx = adj_taps(qx, xs, wx);
    const float* mrow = maps + (size_t)b * (L_ * P_) + l * P_;
    float s = 0.f;
    for (int i = 0; i < ny; ++i) {
        float rs = 0.f;
        for (int j = 0; j < nx; ++j)
            rs = fmaf(wx[j], mrow[ys[i] * 28 + xs[j]], rs);
        s = fmaf(wy[i], rs, s);
    }
    Mp[(size_t)b * (9 * Q_) + r] = s;
}

// ===================== K_E (v13, kept): direct-global MFMA + coalesced af
// blocks [0,1024): l4 (b, 32 grps of 64) K=196 vs Mp.
// blocks [1024,1536): l3, b=idx>>4, grp 0..15, K=784 (4 chunks, acc carried).
__global__ __launch_bounds__(256, 3) void kE(
        const float* __restrict__ l3, const float* __restrict__ l4,
        const float* __restrict__ maps, const float* __restrict__ Mp,
        const float* __restrict__ mod,
        float* __restrict__ out_af, float* __restrict__ mf) {
    __shared__ float sAf[576];        // 2304 B: block's 64ch x 9l af tile
    int bid = blockIdx.x;
    int t = threadIdx.x;
    int wave = t >> 6, lane = t & 63;
    int row16 = lane & 15, quad = lane >> 4;

    bool isl4 = (bid < 1024);
    int b, c0, nchunk, cglob0, pitch;
    const float* xsrc; const float* bsrc;
    if (isl4) {
        b = bid >> 5; c0 = (bid & 31) * 64; nchunk = 1;
        xsrc = l4 + ((size_t)b * C4_ + c0) * Q_;
        bsrc = Mp + (size_t)b * (9 * Q_);
        pitch = Q_;
        cglob0 = c0;
    } else {
        int idx = bid - 1024;
        b = idx >> 4; c0 = (idx & 15) * 64; nchunk = 4;
        xsrc = l3 + ((size_t)b * C3_ + c0) * P_;
        bsrc = maps + (size_t)b * (L_ * P_);
        pitch = P_;
        cglob0 = C4_ + c0;
    }
    const float* arow = xsrc + (size_t)(wave * 16 + row16) * pitch;
    const float* brow = bsrc + (size_t)row16 * pitch;   // valid if row16 < 9

    f32x4 acc = {0.f, 0.f, 0.f, 0.f};
    for (int h = 0; h < nchunk; ++h) {
        int koff = h * 196;
        float4 a[13];
#pragma unroll
        for (int s = 0; s < 6; ++s) {
            int k0 = koff + s * 32 + quad * 8;
            a[2 * s]     = *(const float4*)(arow + k0);
            a[2 * s + 1] = *(const float4*)(arow + k0 + 4);
        }
        a[12] = make_float4(0.f, 0.f, 0.f, 0.f);
        if (quad == 0) a[12] = *(const float4*)(arow + koff + 192);

        bf16x8 bfr[7];
#pragma unroll
        for (int s = 0; s < 7; ++s) {
            int k0 = s * 32 + quad * 8;
            bf16x8 bv = {0, 0, 0, 0, 0, 0, 0, 0};
            if (row16 < 9) {
                const float* bp = brow + koff + k0;
                if (s < 6) {
                    float4 b0 = *(const float4*)(bp);
                    float4 b1 = *(const float4*)(bp + 4);
                    bv[0] = f2bf(b0.x); bv[1] = f2bf(b0.y);
                    bv[2] = f2bf(b0.z); bv[3] = f2bf(b0.w);
                    bv[4] = f2bf(b1.x); bv[5] = f2bf(b1.y);
                    bv[6] = f2bf(b1.z); bv[7] = f2bf(b1.w);
                } else if (quad == 0) {        // k0=192: cols 192..195 only
                    float4 b0 = *(const float4*)(bp);
                    bv[0] = f2bf(b0.x); bv[1] = f2bf(b0.y);
                    bv[2] = f2bf(b0.z); bv[3] = f2bf(b0.w);
                }
            }
            bfr[s] = bv;
        }

#pragma unroll
        for (int s = 0; s < 7; ++s) {
            bf16x8 av = {0, 0, 0, 0, 0, 0, 0, 0};
            if (s < 6) {
                float4 a0 = a[2 * s], a1 = a[2 * s + 1];
                av[0] = f2bf(a0.x); av[1] = f2bf(a0.y);
                av[2] = f2bf(a0.z); av[3] = f2bf(a0.w);
                av[4] = f2bf(a1.x); av[5] = f2bf(a1.y);
                av[6] = f2bf(a1.z); av[7] = f2bf(a1.w);
            } else if (quad == 0) {
                float4 a0 = a[12];
                av[0] = f2bf(a0.x); av[1] = f2bf(a0.y);
                av[2] = f2bf(a0.z); av[3] = f2bf(a0.w);
            }
            acc = __builtin_amdgcn_mfma_f32_16x16x32_bf16(av, bfr[s], acc,
                                                          0, 0, 0);
        }
    }

    // ---- epilogue: af via LDS -> coalesced float4; mf via shfl tree ----
    int l = row16;
    int lc = wave * 16 + quad * 4;        // local channel base (0..60)
    float afv[4];
#pragma unroll
    for (int r = 0; r < 4; ++r) afv[r] = acc[r] * (1.f / 784.f);
    if (l < 9) {
#pragma unroll
        for (int r = 0; r < 4; ++r) sAf[(lc + r) * 9 + l] = afv[r];
    }
    int cg = cglob0 + lc;
    float term[4];
#pragma unroll
    for (int r = 0; r < 4; ++r)
        term[r] = (l < 8) ? afv[r] * mod[(size_t)(cg + r) * 9 + l] : 0.f;
#pragma unroll
    for (int s = 1; s < 16; s <<= 1)
#pragma unroll
        for (int r = 0; r < 4; ++r) term[r] += __shfl_xor(term[r], s);
    if (row16 == 0) {
#pragma unroll
        for (int r = 0; r < 4; ++r)
            mf[(size_t)b * C_ + cg + r] = term[r] * 0.125f;
    }
    __syncthreads();
    // block's af span: 576 contiguous floats at (b*C + cglob0)*9
    size_t obase = ((size_t)b * C_ + cglob0) * 9;   // multiple of 4
    if (t < 144)
        ((float4*)(out_af + obase))[t] = ((const float4*)sAf)[t];
}

// ============== K_F (v9): attr = mf @ attr_w.T, attr_w staged ONCE per block
__global__ __launch_bounds__(256) void kF(
        const float* __restrict__ mf, const float* __restrict__ attr_w,
        const float* __restrict__ attr_b, float* __restrict__ out_attr) {
    __shared__ float sw[C_];               // 12288 B
    int a = blockIdx.x, t = threadIdx.x;
    const float4* wr = (const float4*)(attr_w + (size_t)a * C_);
#pragma unroll
    for (int i = 0; i < 3; ++i)            // 768 float4 = 3 x 256
        ((float4*)sw)[t + i * 256] = wr[t + i * 256];
    __syncthreads();

    int b = t >> 3, j = t & 7;             // 8 lanes per batch
    const float* mrow = mf + (size_t)b * C_;
    float acc = 0.f;
#pragma unroll 8
    for (int m = 0; m < 96; ++m) {         // k = j*4 + m*32 covers K once
        int k = j * 4 + m * 32;
        float4 mv = *(const float4*)(mrow + k);
        float4 wv = *(const float4*)(sw + k);   // broadcast across b-groups
        acc += mv.x * wv.x + mv.y * wv.y + mv.z * wv.z + mv.w * wv.w;
    }
    acc += __shfl_xor(acc, 1);
    acc += __shfl_xor(acc, 2);
    acc += __shfl_xor(acc, 4);
    if (j == 0) out_attr[(size_t)b * A_ + a] = acc + attr_b[a];
}

// ---------------------------------------------- K_G: class = attr @ class_w.T
__global__ __launch_bounds__(256) void kG(
        const float* __restrict__ attr, const float* __restrict__ class_w,
        float* __restrict__ out_class) {
    int idx = blockIdx.x * 4 + (threadIdx.x >> 6);   // idx = b*200 + n
    int lane = threadIdx.x & 63;
    int b = idx / NC_, n = idx % NC_;
    float acc = 0.f;
    for (int a = lane; a < A_; a += 64)
        acc += attr[b * A_ + a] * class_w[n * A_ + a];
    acc += __shfl_xor(acc, 1);  acc += __shfl_xor(acc, 2);
    acc += __shfl_xor(acc, 4);  acc += __shfl_xor(acc, 8);
    acc += __shfl_xor(acc, 16); acc += __shfl_xor(acc, 32);
    if (lane == 0) out_class[idx] = acc;
}

extern "C" void kernel_launch(void* const* d_in, const int* in_sizes, int n_in,
                              void* d_out, int out_size, void* d_ws, size_t ws_size,
                              hipStream_t stream) {
    (void)in_sizes; (void)n_in; (void)out_size; (void)ws_size;
    const float* l3         = (const float*)d_in[0];
    const float* l4         = (const float*)d_in[1];
    const float* conv_w     = (const float*)d_in[2];
    const float* modulation = (const float*)d_in[3];
    const float* attr_w     = (const float*)d_in[4];
    const float* attr_b     = (const float*)d_in[5];
    const float* class_w    = (const float*)d_in[6];
    float* out = (float*)d_out;
    float* ws  = (float*)d_ws;
    float* asq    = ws + ASQ_OFF;
    float* mf     = ws + MF_OFF;
    float* logits = ws + LOGITS_OFF;
    float* Y      = ws + Y_OFF;
    float* Mp     = ws + MP_OFF;

    zK<<<285, 256, 0, stream>>>(conv_w, logits /* zero base: logits+Y */, asq);
    kA<<<1536, 256, 0, stream>>>(l3, l4, conv_w, logits, Y);
    kC<<<98, 256, 0, stream>>>(logits, Y, asq, out + MAPS_OFF);
    kD<<<221, 256, 0, stream>>>(out + MAPS_OFF, Mp);
    kE<<<1536, 256, 0, stream>>>(l3, l4, out + MAPS_OFF, Mp, modulation,
                                 out + AF_OFF, mf);
    kF<<<A_, 256, 0, stream>>>(mf, attr_w, attr_b, out + ATTR_OFF);
    kG<<<(B_ * NC_) / 4, 256, 0, stream>>>(out + ATTR_OFF, class_w,
                                           out + CLASS_OFF);
}